// Round 11
// baseline (363.429 us; speedup 1.0000x reference)
//
#include <hip/hip_runtime.h>
#include <hip/hip_bf16.h>

// Fused causal self-attention, B=2, S=4096, E=1024, D=64 (single head).
// R11: combined instrumentation + candidate.
//   - qkv_proj2 (NEW candidate): 512 blk x 256 thr (2 blk/CU), K-chunk=64,
//     deep staging (7x16B/thread in flight). Runs FIRST; its Qb/Kb/Vt output
//     is fully overwritten by old qkv -> masked (no correctness risk yet).
//   - qkv_proj (OLD, frozen) x12: last writer (verified output = R7 path);
//     12 counter rows; rep1 cold-x vs reps2+ L3-warm discriminates
//     x-latency-bound vs structural-latency-bound.
//   - wprep/attn/combine frozen from R7.

typedef short short8 __attribute__((ext_vector_type(8)));
typedef float f32x2 __attribute__((ext_vector_type(2)));
typedef float f32x4 __attribute__((ext_vector_type(4)));
typedef float f32x16 __attribute__((ext_vector_type(16)));
typedef unsigned int uint4e __attribute__((ext_vector_type(4)));
typedef unsigned short ushort4e __attribute__((ext_vector_type(4)));

#define NEGINF (-3.0e38f)
#define SCQ 0.18033688011112042f   // 0.125 * log2(e): S in log2 domain -> exp2

static __device__ __forceinline__ unsigned short f2bf(float f) {
  __hip_bfloat16 h = __float2bfloat16(f);
  return __builtin_bit_cast(unsigned short, h);
}
static __device__ __forceinline__ f32x16 mfma32(short8 a, short8 b, f32x16 c) {
  return __builtin_amdgcn_mfma_f32_32x32x16_bf16(a, b, c, 0, 0, 0);
}

// ---------------- Kernel 1: W prep (coalesced transpose via LDS) -------------
__global__ __launch_bounds__(256) void wprep_kernel(
    const float* __restrict__ Wq, const float* __restrict__ Wk,
    const float* __restrict__ Wv, unsigned short* __restrict__ Wt) {
  int w = blockIdx.x >> 3;
  int kc = blockIdx.x & 7;
  int k0 = kc * 128;
  const float* W = (w == 0) ? Wq : ((w == 1) ? Wk : Wv);
  float sc = (w == 0) ? SCQ : 1.0f;

  __shared__ unsigned short lt[128][66];
#pragma unroll
  for (int i = 0; i < 32; ++i) {
    int e = i * 256 + threadIdx.x;
    int k = e >> 6, n = e & 63;
    lt[k][n] = f2bf(W[(size_t)(k0 + k) * 64 + n] * sc);
  }
  __syncthreads();
#pragma unroll
  for (int i = 0; i < 32; ++i) {
    int e = i * 256 + threadIdx.x;
    int n = e >> 7, k = e & 127;
    Wt[(size_t)(w * 64 + n) * 1024 + k0 + k] = lt[k][n];
  }
}

// ---------------- Kernel 2a: QKV projection (OLD, frozen from R7) ------------
__global__ __launch_bounds__(512) void qkv_proj_kernel(
    const float* __restrict__ x, const unsigned short* __restrict__ Wt,
    unsigned short* __restrict__ Qb, unsigned short* __restrict__ Kb,
    unsigned short* __restrict__ Vt) {
  int tid = threadIdx.x;
  int lane = tid & 63;
  int wv = tid >> 6;          // 0..7
  int rt = wv >> 2;           // row half (16 rows)
  int cg = wv & 3;            // col group (48 cols = 3 tiles)
  int r = lane & 15;
  int hi = lane >> 4;
  int sbase = blockIdx.x * 32;

  __shared__ alignas(16) unsigned short xs[2][32][40];    //  5.1 KB
  __shared__ alignas(16) unsigned short wsl[2][192][40];  // 30.7 KB

  int xrow = tid >> 4;              // 0..31
  int xcol = (tid & 15) * 2;        // 0..30
  int p1 = tid;                     // Wt piece (row = p>>2, off = (p&3)*8)
  int p2 = tid + 512;               // second piece for tid < 256
  const float* xg = x + (size_t)(sbase + xrow) * 1024 + xcol;

  f32x4 acc[3];
#pragma unroll
  for (int t = 0; t < 3; ++t)
#pragma unroll
    for (int i = 0; i < 4; ++i) acc[t][i] = 0.f;

  {
    f32x2 xv = *(const f32x2*)(xg);
    unsigned int pk = (unsigned int)f2bf(xv[0]) | ((unsigned int)f2bf(xv[1]) << 16);
    *(unsigned int*)&xs[0][xrow][xcol] = pk;
    short8 wva = *(const short8*)(Wt + (size_t)(p1 >> 2) * 1024 + (p1 & 3) * 8);
    *(short8*)&wsl[0][p1 >> 2][(p1 & 3) * 8] = wva;
    if (tid < 256) {
      short8 wvb = *(const short8*)(Wt + (size_t)(p2 >> 2) * 1024 + (p2 & 3) * 8);
      *(short8*)&wsl[0][p2 >> 2][(p2 & 3) * 8] = wvb;
    }
  }
  __syncthreads();

  for (int c = 0; c < 32; ++c) {
    int cur = c & 1;
    bool has_next = (c + 1) < 32;
    f32x2 xv;
    short8 wva, wvb;
    if (has_next) {
      int k0 = (c + 1) * 32;
      xv = *(const f32x2*)(xg + k0);
      wva = *(const short8*)(Wt + (size_t)(p1 >> 2) * 1024 + k0 + (p1 & 3) * 8);
      if (tid < 256)
        wvb = *(const short8*)(Wt + (size_t)(p2 >> 2) * 1024 + k0 + (p2 & 3) * 8);
    }
    short8 af = *(const short8*)&xs[cur][rt * 16 + r][hi * 8];
#pragma unroll
    for (int tt = 0; tt < 3; ++tt) {
      short8 bf = *(const short8*)&wsl[cur][(cg * 3 + tt) * 16 + r][hi * 8];
      acc[tt] = __builtin_amdgcn_mfma_f32_16x16x32_bf16(af, bf, acc[tt], 0, 0, 0);
    }
    if (has_next) {
      int nb = cur ^ 1;
      unsigned int pk = (unsigned int)f2bf(xv[0]) | ((unsigned int)f2bf(xv[1]) << 16);
      *(unsigned int*)&xs[nb][xrow][xcol] = pk;
      *(short8*)&wsl[nb][p1 >> 2][(p1 & 3) * 8] = wva;
      if (tid < 256) *(short8*)&wsl[nb][p2 >> 2][(p2 & 3) * 8] = wvb;
    }
    __syncthreads();
  }

  int lr = rt * 16 + hi * 4;
#pragma unroll
  for (int tt = 0; tt < 3; ++tt) {
    int gt = cg * 3 + tt;
    if (gt < 8) {
      unsigned short* dst = (gt < 4) ? Qb : Kb;
      int col = (gt & 3) * 16 + r;
#pragma unroll
      for (int v = 0; v < 4; ++v)
        dst[(size_t)(sbase + lr + v) * 64 + col] = f2bf(acc[tt][v]);
    } else {
      int d = (gt - 8) * 16 + r;
      ushort4e pk;
#pragma unroll
      for (int v = 0; v < 4; ++v) pk[v] = f2bf(acc[tt][v]);
      int bidx = sbase >> 12;
      int so = (sbase & 4095) + lr;
      *(ushort4e*)(Vt + ((size_t)(bidx * 64 + d)) * 4096 + so) = pk;
    }
  }
}

// ---------------- Kernel 2b: QKV projection (NEW candidate) ------------------
// 512 blocks x 256 threads (4 waves, 2 blocks/CU). Block = 16 rows x 192 cols;
// K-chunks of 64 (16 chunks), double-buffered LDS with padded 72-short rows.
// Per chunk per thread: 1 f32x4 x-load + 6 short8 Wt-loads = 112B in flight.
// Wave w owns 3 tiles (48 cols) x 16 rows; 6 MFMA/chunk.
__global__ __launch_bounds__(256, 2) void qkv_proj2_kernel(
    const float* __restrict__ x, const unsigned short* __restrict__ Wt,
    unsigned short* __restrict__ Qb, unsigned short* __restrict__ Kb,
    unsigned short* __restrict__ Vt) {
  int tid = threadIdx.x;
  int lane = tid & 63;
  int w = tid >> 6;           // wave 0..3 = col group of 48
  int r = lane & 15;
  int hi = lane >> 4;
  int sbase = blockIdx.x * 16;

  __shared__ alignas(16) unsigned short xs[2][16][72];     //  4.5 KB
  __shared__ alignas(16) unsigned short wsh[2][192][72];   // 54.0 KB

  int xrow = tid >> 4;              // 0..15
  int xcol = (tid & 15) * 4;        // 0..60
  const float* xg = x + (size_t)(sbase + xrow) * 1024 + xcol;

  f32x4 acc[3];
#pragma unroll
  for (int t = 0; t < 3; ++t)
#pragma unroll
    for (int i = 0; i < 4; ++i) acc[t][i] = 0.f;

  // ---- stage chunk 0 ----
  {
    f32x4 xv = *(const f32x4*)(xg);
    ushort4e xp;
#pragma unroll
    for (int j = 0; j < 4; ++j) xp[j] = f2bf(xv[j]);
    *(ushort4e*)&xs[0][xrow][xcol] = xp;
#pragma unroll
    for (int i = 0; i < 6; ++i) {
      int p = tid + 256 * i;        // 0..1535: row = p>>3, off = (p&7)*8
      short8 wv = *(const short8*)(Wt + (size_t)(p >> 3) * 1024 + (p & 7) * 8);
      *(short8*)&wsh[0][p >> 3][(p & 7) * 8] = wv;
    }
  }
  __syncthreads();

  for (int c = 0; c < 16; ++c) {
    int cur = c & 1;
    bool has_next = (c + 1) < 16;
    f32x4 xv;
    short8 wv[6];
    if (has_next) {                 // issue next-chunk loads (deep in-flight)
      int k0 = (c + 1) * 64;
      xv = *(const f32x4*)(xg + k0);
#pragma unroll
      for (int i = 0; i < 6; ++i) {
        int p = tid + 256 * i;
        wv[i] = *(const short8*)(Wt + (size_t)(p >> 3) * 1024 + k0 + (p & 7) * 8);
      }
    }
    // compute chunk c: 3 tiles x 2 k-steps
    short8 af0 = *(const short8*)&xs[cur][r][hi * 8];
    short8 af1 = *(const short8*)&xs[cur][r][32 + hi * 8];
#pragma unroll
    for (int tt = 0; tt < 3; ++tt) {
      const unsigned short* bp = &wsh[cur][w * 48 + tt * 16 + r][hi * 8];
      short8 bf0 = *(const short8*)bp;
      short8 bf1 = *(const short8*)(bp + 32);
      acc[tt] = __builtin_amdgcn_mfma_f32_16x16x32_bf16(af0, bf0, acc[tt], 0, 0, 0);
      acc[tt] = __builtin_amdgcn_mfma_f32_16x16x32_bf16(af1, bf1, acc[tt], 0, 0, 0);
    }
    if (has_next) {
      int nb = cur ^ 1;
      ushort4e xp;
#pragma unroll
      for (int j = 0; j < 4; ++j) xp[j] = f2bf(xv[j]);
      *(ushort4e*)&xs[nb][xrow][xcol] = xp;
#pragma unroll
      for (int i = 0; i < 6; ++i) {
        int p = tid + 256 * i;
        *(short8*)&wsh[nb][p >> 3][(p & 7) * 8] = wv[i];
      }
    }
    __syncthreads();
  }

  // ---- epilogue (same math as R7, rt removed) ----
  int lr = hi * 4;
#pragma unroll
  for (int tt = 0; tt < 3; ++tt) {
    int gt = w * 3 + tt;
    if (gt < 8) {
      unsigned short* dst = (gt < 4) ? Qb : Kb;
      int col = (gt & 3) * 16 + r;
#pragma unroll
      for (int v = 0; v < 4; ++v)
        dst[(size_t)(sbase + lr + v) * 64 + col] = f2bf(acc[tt][v]);
    } else {
      int d = (gt - 8) * 16 + r;
      ushort4e pk;
#pragma unroll
      for (int v = 0; v < 4; ++v) pk[v] = f2bf(acc[tt][v]);
      int bidx = sbase >> 12;
      int so = (sbase & 4095) + lr;
      *(ushort4e*)(Vt + ((size_t)(bidx * 64 + d)) * 4096 + so) = pk;
    }
  }
}

// ---------------- Kernel 3: flash attention (frozen from R6/R7) --------------
__global__ __launch_bounds__(256, 2) void attn_kernel(
    const unsigned short* __restrict__ Qb, const unsigned short* __restrict__ Kb,
    const unsigned short* __restrict__ Vt, float* __restrict__ Opart,
    float* __restrict__ Mpart, float* __restrict__ Lpart) {
  int bid = blockIdx.x;             // 0..1023
  int q = 127 - (bid >> 3);         // heavy q first
  int b = (bid >> 2) & 1;
  int hh = bid & 3;
  int lane = threadIdx.x & 63;
  int p = threadIdx.x >> 6;         // 0..3
  int g = hh * 4 + p;               // KV part 0..15
  int ql = lane & 31;
  int h = lane >> 5;
  int sbase = q * 32;

  __shared__ float sm[4][32];
  __shared__ float sl[4][32];
  __shared__ alignas(16) float Op[4][32][68];

  const unsigned short* Qp = Qb + ((size_t)(b * 4096 + sbase + ql)) * 64 + h * 8;
  short8 qf0 = *(const short8*)(Qp);
  short8 qf1 = *(const short8*)(Qp + 16);
  short8 qf2 = *(const short8*)(Qp + 32);
  short8 qf3 = *(const short8*)(Qp + 48);

  f32x16 o0, o1;
#pragma unroll
  for (int i = 0; i < 16; ++i) { o0[i] = 0.f; o1[i] = 0.f; }
  float m = NEGINF, l = 0.f;

  int npairs = (q + 2) >> 1;
  const unsigned short* Kbb = Kb + (size_t)b * 4096 * 64;
  const unsigned short* Vbb = Vt + ((size_t)(b * 64 + ql)) * 4096 + h * 8;

  short8 k0a, k0b, k0c, k0d, k1a, k1b, k1c, k1d;
  {
    const unsigned short* Kp = Kbb + (size_t)(g * 64 + ql) * 64 + h * 8;
    k0a = *(const short8*)(Kp);
    k0b = *(const short8*)(Kp + 16);
    k0c = *(const short8*)(Kp + 32);
    k0d = *(const short8*)(Kp + 48);
    k1a = *(const short8*)(Kp + 2048);
    k1b = *(const short8*)(Kp + 2048 + 16);
    k1c = *(const short8*)(Kp + 2048 + 32);
    k1d = *(const short8*)(Kp + 2048 + 48);
  }

  for (int j = g; j < npairs; j += 16) {
    int kbase = j * 64;
    const unsigned short* Vp = Vbb + kbase;
    short8 vf0 = *(const short8*)(Vp);
    short8 vf1 = *(const short8*)(Vp + 16);
    short8 vf2 = *(const short8*)(Vp + 32);
    short8 vf3 = *(const short8*)(Vp + 48);
    short8 vg0 = *(const short8*)(Vp + 32 * 4096);
    short8 vg1 = *(const short8*)(Vp + 32 * 4096 + 16);
    short8 vg2 = *(const short8*)(Vp + 32 * 4096 + 32);
    short8 vg3 = *(const short8*)(Vp + 32 * 4096 + 48);

    f32x16 st0, st1;
#pragma unroll
    for (int i = 0; i < 16; ++i) { st0[i] = 0.f; st1[i] = 0.f; }
    __builtin_amdgcn_s_setprio(1);
    st0 = mfma32(k0a, qf0, st0);
    st0 = mfma32(k0b, qf1, st0);
    st0 = mfma32(k0c, qf2, st0);
    st0 = mfma32(k0d, qf3, st0);
    st1 = mfma32(k1a, qf0, st1);
    st1 = mfma32(k1b, qf1, st1);
    st1 = mfma32(k1c, qf2, st1);
    st1 = mfma32(k1d, qf3, st1);
    __builtin_amdgcn_s_setprio(0);

    if (j + 16 < npairs) {
      const unsigned short* Kp = Kbb + (size_t)((j + 16) * 64 + ql) * 64 + h * 8;
      k0a = *(const short8*)(Kp);
      k0b = *(const short8*)(Kp + 16);
      k0c = *(const short8*)(Kp + 32);
      k0d = *(const short8*)(Kp + 48);
      k1a = *(const short8*)(Kp + 2048);
      k1b = *(const short8*)(Kp + 2048 + 16);
      k1c = *(const short8*)(Kp + 2048 + 32);
      k1d = *(const short8*)(Kp + 2048 + 48);
    }

    if (2 * j == q) {
#pragma unroll
      for (int rg = 0; rg < 16; ++rg) {
        int kvl = (rg & 3) + 8 * (rg >> 2) + 4 * h;
        if (kvl > ql) st0[rg] = NEGINF;
        st1[rg] = NEGINF;
      }
    } else if (2 * j + 1 == q) {
#pragma unroll
      for (int rg = 0; rg < 16; ++rg) {
        int kvl = (rg & 3) + 8 * (rg >> 2) + 4 * h;
        if (kvl > ql) st1[rg] = NEGINF;
      }
    }

    float mx[16];
#pragma unroll
    for (int i = 0; i < 16; ++i) mx[i] = fmaxf(st0[i], st1[i]);
#pragma unroll
    for (int s = 8; s >= 1; s >>= 1)
#pragma unroll
      for (int i = 0; i < s; ++i) mx[i] = fmaxf(mx[i], mx[i + s]);
    float tm = fmaxf(mx[0], __shfl_xor(mx[0], 32));
    float nm = fmaxf(m, tm);
    float alpha = exp2f(m - nm);
#pragma unroll
    for (int i = 0; i < 16; ++i) {
      st0[i] = exp2f(st0[i] - nm);
      st1[i] = exp2f(st1[i] - nm);
    }
    float sv[16];
#pragma unroll
    for (int i = 0; i < 16; ++i) sv[i] = st0[i] + st1[i];
#pragma unroll
    for (int s = 8; s >= 1; s >>= 1)
#pragma unroll
      for (int i = 0; i < s; ++i) sv[i] += sv[i + s];
    float sum = sv[0] + __shfl_xor(sv[0], 32);
    l = l * alpha + sum;
    m = nm;
#pragma unroll
    for (int i = 0; i < 16; ++i) { o0[i] *= alpha; o1[i] *= alpha; }

    unsigned int pw0[8], pw1[8], sw0[8], sw1[8];
#pragma unroll
    for (int t = 0; t < 8; ++t) {
      pw0[t] = (unsigned int)f2bf(st0[2 * t]) | ((unsigned int)f2bf(st0[2 * t + 1]) << 16);
      pw1[t] = (unsigned int)f2bf(st1[2 * t]) | ((unsigned int)f2bf(st1[2 * t + 1]) << 16);
    }
#pragma unroll
    for (int t = 0; t < 8; ++t) {
      sw0[t] = __shfl_xor(pw0[t], 32);
      sw1[t] = __shfl_xor(pw1[t], 32);
    }
    uint4e bw0 = {h ? sw0[2] : pw0[0], h ? sw0[3] : pw0[1], h ? pw0[2] : sw0[0], h ? pw0[3] : sw0[1]};
    uint4e bw1 = {h ? sw0[6] : pw0[4], h ? sw0[7] : pw0[5], h ? pw0[6] : sw0[4], h ? pw0[7] : sw0[5]};
    uint4e bw2 = {h ? sw1[2] : pw1[0], h ? sw1[3] : pw1[1], h ? pw1[2] : sw1[0], h ? pw1[3] : sw1[1]};
    uint4e bw3 = {h ? sw1[6] : pw1[4], h ? sw1[7] : pw1[5], h ? pw1[6] : sw1[4], h ? pw1[7] : sw1[5]};
    short8 pb0 = __builtin_bit_cast(short8, bw0);
    short8 pb1 = __builtin_bit_cast(short8, bw1);
    short8 pb2 = __builtin_bit_cast(short8, bw2);
    short8 pb3 = __builtin_bit_cast(short8, bw3);

    __builtin_amdgcn_s_setprio(1);
    o0 = mfma32(vf0, pb0, o0);
    o0 = mfma32(vf1, pb1, o0);
    o0 = mfma32(vf2, pb2, o0);
    o0 = mfma32(vf3, pb3, o0);
    o1 = mfma32(vg0, pb0, o1);
    o1 = mfma32(vg1, pb1, o1);
    o1 = mfma32(vg2, pb2, o1);
    o1 = mfma32(vg3, pb3, o1);
    __builtin_amdgcn_s_setprio(0);
  }

  if (h == 0) sm[p][ql] = m;
  __syncthreads();
  float gm = sm[0][ql];
#pragma unroll
  for (int i = 1; i < 4; ++i) gm = fmaxf(gm, sm[i][ql]);
  float alpha = exp2f(m - gm);
  if (h == 0) sl[p][ql] = alpha * l;
  float* Ob = &Op[p][ql][0];
#pragma unroll
  for (int u = 0; u < 4; ++u) {
    f32x4 w0 = {alpha * o0[4 * u], alpha * o0[4 * u + 1], alpha * o0[4 * u + 2], alpha * o0[4 * u + 3]};
    *(f32x4*)(Ob + u * 8 + h * 4) = w0;
    f32x4 w1 = {alpha * o1[4 * u], alpha * o1[4 * u + 1], alpha * o1[4 * u + 2], alpha * o1[4 * u + 3]};
    *(f32x4*)(Ob + 32 + u * 8 + h * 4) = w1;
  }
  __syncthreads();

  float* Od = Opart + (size_t)bid * 2048;
#pragma unroll
  for (int i = 0; i < 2; ++i) {
    int task = threadIdx.x + i * 256;
    int row = task >> 4;
    int c4 = (task & 15) * 4;
    f32x4 accv = *(const f32x4*)(&Op[0][row][c4]);
#pragma unroll
    for (int pp = 1; pp < 4; ++pp) accv += *(const f32x4*)(&Op[pp][row][c4]);
    *(f32x4*)(Od + row * 64 + c4) = accv;
  }
  if (threadIdx.x < 32) {
    int row = threadIdx.x;
    float gmv = fmaxf(fmaxf(sm[0][row], sm[1][row]), fmaxf(sm[2][row], sm[3][row]));
    Mpart[(size_t)bid * 32 + row] = gmv;
    Lpart[(size_t)bid * 32 + row] = sl[0][row] + sl[1][row] + sl[2][row] + sl[3][row];
  }
}

// ---------------- Kernel 4: combine 4 partials per q-tile --------------------
__global__ __launch_bounds__(256) void combine_kernel(
    const float* __restrict__ Opart, const float* __restrict__ Mpart,
    const float* __restrict__ Lpart, float* __restrict__ out) {
  int gid = blockIdx.x * 256 + threadIdx.x;   // 0..131071
  int c4 = (gid & 15) * 4;
  int row = gid >> 4;                         // b*4096 + s
  int r = row & 31;
  int qg = row >> 5;                          // b*128 + q
  int b = qg >> 7, q = qg & 127;
  int base = (127 - q) * 8 + b * 4;           // 4 partial blocks

  float mm[4];
  float gm = NEGINF;
#pragma unroll
  for (int i = 0; i < 4; ++i) {
    mm[i] = Mpart[(size_t)(base + i) * 32 + r];
    gm = fmaxf(gm, mm[i]);
  }
  float L = 0.f;
  f32x4 o = {0.f, 0.f, 0.f, 0.f};
#pragma unroll
  for (int i = 0; i < 4; ++i) {
    float e = exp2f(mm[i] - gm);
    L += e * Lpart[(size_t)(base + i) * 32 + r];
    f32x4 ov = *(const f32x4*)(Opart + (size_t)(base + i) * 2048 + r * 64 + c4);
    o += e * ov;
  }
  float invl = 1.0f / L;
  f32x4 res = {o[0] * invl, o[1] * invl, o[2] * invl, o[3] * invl};
  *(f32x4*)(out + (size_t)row * 64 + c4) = res;
}

// ---------------- launcher ---------------------------------------------------
extern "C" void kernel_launch(void* const* d_in, const int* in_sizes, int n_in,
                              void* d_out, int out_size, void* d_ws, size_t ws_size,
                              hipStream_t stream) {
  const float* x  = (const float*)d_in[0];
  const float* Wq = (const float*)d_in[1];
  const float* Wk = (const float*)d_in[2];
  const float* Wv = (const float*)d_in[3];
  float* out = (float*)d_out;

  if (ws_size < 12189696) return;  // tripwire

  char* ws = (char*)d_ws;
  unsigned short* Wt = (unsigned short*)(ws + 0);          //   393216 B
  unsigned short* Qb = (unsigned short*)(ws + 393216);     //  1048576 B
  unsigned short* Kb = (unsigned short*)(ws + 1441792);    //  1048576 B
  unsigned short* Vt = (unsigned short*)(ws + 2490368);    //  1048576 B
  float* Opart = (float*)(ws + 3538944);                   //  8388608 B
  float* Mpart = (float*)(ws + 11927552);                  //   131072 B
  float* Lpart = (float*)(ws + 12058624);                  //   131072 B

  wprep_kernel<<<24, 256, 0, stream>>>(Wq, Wk, Wv, Wt);
  // NEW candidate first (masked: old fully overwrites Qb/Kb/Vt below).
  qkv_proj2_kernel<<<512, 256, 0, stream>>>(x, Wt, Qb, Kb, Vt);
  // OLD qkv x12 (instrumentation; last writer -> verified output = R7 path).
  // rep1 = cold-x, reps 2+ = L3-warm x: the per-dispatch FETCH/dur split
  // discriminates x-latency-bound vs structural-latency-bound.
  for (int rep = 0; rep < 12; ++rep)
    qkv_proj_kernel<<<256, 512, 0, stream>>>(x, Wt, Qb, Kb, Vt);
  attn_kernel<<<1024, 256, 0, stream>>>(Qb, Kb, Vt, Opart, Mpart, Lpart);
  combine_kernel<<<512, 256, 0, stream>>>(Opart, Mpart, Lpart, out);
}

// Round 12
// 192.807 us; speedup vs baseline: 1.8849x; 1.8849x over previous
//
#include <hip/hip_runtime.h>
#include <hip/hip_bf16.h>

// Fused causal self-attention, B=2, S=4096, E=1024, D=64 (single head).
// R12: internal-repeat instrumentation. attn_kernel takes runtime nrep (=4):
//   whole body repeated idempotently INSIDE one dispatch -> ~4x-long counter
//   row enters rocprof top-5 (beats the 43us fill rows that censored all
//   kernel counters through R11). Row/4 = gapless attn dur; 22.4 - that =
//   per-dispatch gap g (resolves Case A/B). qkv2 masked x1 for timing.
//   Production path byte-identical to R7 (zero correctness risk).

typedef short short8 __attribute__((ext_vector_type(8)));
typedef float f32x2 __attribute__((ext_vector_type(2)));
typedef float f32x4 __attribute__((ext_vector_type(4)));
typedef float f32x16 __attribute__((ext_vector_type(16)));
typedef unsigned int uint4e __attribute__((ext_vector_type(4)));
typedef unsigned short ushort4e __attribute__((ext_vector_type(4)));

#define NEGINF (-3.0e38f)
#define SCQ 0.18033688011112042f   // 0.125 * log2(e): S in log2 domain -> exp2

static __device__ __forceinline__ unsigned short f2bf(float f) {
  __hip_bfloat16 h = __float2bfloat16(f);
  return __builtin_bit_cast(unsigned short, h);
}
static __device__ __forceinline__ f32x16 mfma32(short8 a, short8 b, f32x16 c) {
  return __builtin_amdgcn_mfma_f32_32x32x16_bf16(a, b, c, 0, 0, 0);
}

// ---------------- Kernel 1: W prep (coalesced transpose via LDS) -------------
__global__ __launch_bounds__(256) void wprep_kernel(
    const float* __restrict__ Wq, const float* __restrict__ Wk,
    const float* __restrict__ Wv, unsigned short* __restrict__ Wt) {
  int w = blockIdx.x >> 3;
  int kc = blockIdx.x & 7;
  int k0 = kc * 128;
  const float* W = (w == 0) ? Wq : ((w == 1) ? Wk : Wv);
  float sc = (w == 0) ? SCQ : 1.0f;

  __shared__ unsigned short lt[128][66];
#pragma unroll
  for (int i = 0; i < 32; ++i) {
    int e = i * 256 + threadIdx.x;
    int k = e >> 6, n = e & 63;
    lt[k][n] = f2bf(W[(size_t)(k0 + k) * 64 + n] * sc);
  }
  __syncthreads();
#pragma unroll
  for (int i = 0; i < 32; ++i) {
    int e = i * 256 + threadIdx.x;
    int n = e >> 7, k = e & 127;
    Wt[(size_t)(w * 64 + n) * 1024 + k0 + k] = lt[k][n];
  }
}

// ---------------- Kernel 2a: QKV projection (OLD prod, frozen from R7) -------
__global__ __launch_bounds__(512) void qkv_proj_kernel(
    const float* __restrict__ x, const unsigned short* __restrict__ Wt,
    unsigned short* __restrict__ Qb, unsigned short* __restrict__ Kb,
    unsigned short* __restrict__ Vt) {
  int tid = threadIdx.x;
  int lane = tid & 63;
  int wv = tid >> 6;
  int rt = wv >> 2;
  int cg = wv & 3;
  int r = lane & 15;
  int hi = lane >> 4;
  int sbase = blockIdx.x * 32;

  __shared__ alignas(16) unsigned short xs[2][32][40];
  __shared__ alignas(16) unsigned short wsl[2][192][40];

  int xrow = tid >> 4;
  int xcol = (tid & 15) * 2;
  int p1 = tid;
  int p2 = tid + 512;
  const float* xg = x + (size_t)(sbase + xrow) * 1024 + xcol;

  f32x4 acc[3];
#pragma unroll
  for (int t = 0; t < 3; ++t)
#pragma unroll
    for (int i = 0; i < 4; ++i) acc[t][i] = 0.f;

  {
    f32x2 xv = *(const f32x2*)(xg);
    unsigned int pk = (unsigned int)f2bf(xv[0]) | ((unsigned int)f2bf(xv[1]) << 16);
    *(unsigned int*)&xs[0][xrow][xcol] = pk;
    short8 wva = *(const short8*)(Wt + (size_t)(p1 >> 2) * 1024 + (p1 & 3) * 8);
    *(short8*)&wsl[0][p1 >> 2][(p1 & 3) * 8] = wva;
    if (tid < 256) {
      short8 wvb = *(const short8*)(Wt + (size_t)(p2 >> 2) * 1024 + (p2 & 3) * 8);
      *(short8*)&wsl[0][p2 >> 2][(p2 & 3) * 8] = wvb;
    }
  }
  __syncthreads();

  for (int c = 0; c < 32; ++c) {
    int cur = c & 1;
    bool has_next = (c + 1) < 32;
    f32x2 xv;
    short8 wva, wvb;
    if (has_next) {
      int k0 = (c + 1) * 32;
      xv = *(const f32x2*)(xg + k0);
      wva = *(const short8*)(Wt + (size_t)(p1 >> 2) * 1024 + k0 + (p1 & 3) * 8);
      if (tid < 256)
        wvb = *(const short8*)(Wt + (size_t)(p2 >> 2) * 1024 + k0 + (p2 & 3) * 8);
    }
    short8 af = *(const short8*)&xs[cur][rt * 16 + r][hi * 8];
#pragma unroll
    for (int tt = 0; tt < 3; ++tt) {
      short8 bf = *(const short8*)&wsl[cur][(cg * 3 + tt) * 16 + r][hi * 8];
      acc[tt] = __builtin_amdgcn_mfma_f32_16x16x32_bf16(af, bf, acc[tt], 0, 0, 0);
    }
    if (has_next) {
      int nb = cur ^ 1;
      unsigned int pk = (unsigned int)f2bf(xv[0]) | ((unsigned int)f2bf(xv[1]) << 16);
      *(unsigned int*)&xs[nb][xrow][xcol] = pk;
      *(short8*)&wsl[nb][p1 >> 2][(p1 & 3) * 8] = wva;
      if (tid < 256) *(short8*)&wsl[nb][p2 >> 2][(p2 & 3) * 8] = wvb;
    }
    __syncthreads();
  }

  int lr = rt * 16 + hi * 4;
#pragma unroll
  for (int tt = 0; tt < 3; ++tt) {
    int gt = cg * 3 + tt;
    if (gt < 8) {
      unsigned short* dst = (gt < 4) ? Qb : Kb;
      int col = (gt & 3) * 16 + r;
#pragma unroll
      for (int v = 0; v < 4; ++v)
        dst[(size_t)(sbase + lr + v) * 64 + col] = f2bf(acc[tt][v]);
    } else {
      int d = (gt - 8) * 16 + r;
      ushort4e pk;
#pragma unroll
      for (int v = 0; v < 4; ++v) pk[v] = f2bf(acc[tt][v]);
      int bidx = sbase >> 12;
      int so = (sbase & 4095) + lr;
      *(ushort4e*)(Vt + ((size_t)(bidx * 64 + d)) * 4096 + so) = pk;
    }
  }
}

// ---------------- Kernel 2b: QKV projection (NEW candidate, masked) ----------
__global__ __launch_bounds__(256, 2) void qkv_proj2_kernel(
    const float* __restrict__ x, const unsigned short* __restrict__ Wt,
    unsigned short* __restrict__ Qb, unsigned short* __restrict__ Kb,
    unsigned short* __restrict__ Vt) {
  int tid = threadIdx.x;
  int lane = tid & 63;
  int w = tid >> 6;
  int r = lane & 15;
  int hi = lane >> 4;
  int sbase = blockIdx.x * 16;

  __shared__ alignas(16) unsigned short xs[2][16][72];
  __shared__ alignas(16) unsigned short wsh[2][192][72];

  int xrow = tid >> 4;
  int xcol = (tid & 15) * 4;
  const float* xg = x + (size_t)(sbase + xrow) * 1024 + xcol;

  f32x4 acc[3];
#pragma unroll
  for (int t = 0; t < 3; ++t)
#pragma unroll
    for (int i = 0; i < 4; ++i) acc[t][i] = 0.f;

  {
    f32x4 xv = *(const f32x4*)(xg);
    ushort4e xp;
#pragma unroll
    for (int j = 0; j < 4; ++j) xp[j] = f2bf(xv[j]);
    *(ushort4e*)&xs[0][xrow][xcol] = xp;
#pragma unroll
    for (int i = 0; i < 6; ++i) {
      int p = tid + 256 * i;
      short8 wv = *(const short8*)(Wt + (size_t)(p >> 3) * 1024 + (p & 7) * 8);
      *(short8*)&wsh[0][p >> 3][(p & 7) * 8] = wv;
    }
  }
  __syncthreads();

  for (int c = 0; c < 16; ++c) {
    int cur = c & 1;
    bool has_next = (c + 1) < 16;
    f32x4 xv;
    short8 wv[6];
    if (has_next) {
      int k0 = (c + 1) * 64;
      xv = *(const f32x4*)(xg + k0);
#pragma unroll
      for (int i = 0; i < 6; ++i) {
        int p = tid + 256 * i;
        wv[i] = *(const short8*)(Wt + (size_t)(p >> 3) * 1024 + k0 + (p & 7) * 8);
      }
    }
    short8 af0 = *(const short8*)&xs[cur][r][hi * 8];
    short8 af1 = *(const short8*)&xs[cur][r][32 + hi * 8];
#pragma unroll
    for (int tt = 0; tt < 3; ++tt) {
      const unsigned short* bp = &wsh[cur][w * 48 + tt * 16 + r][hi * 8];
      short8 bf0 = *(const short8*)bp;
      short8 bf1 = *(const short8*)(bp + 32);
      acc[tt] = __builtin_amdgcn_mfma_f32_16x16x32_bf16(af0, bf0, acc[tt], 0, 0, 0);
      acc[tt] = __builtin_amdgcn_mfma_f32_16x16x32_bf16(af1, bf1, acc[tt], 0, 0, 0);
    }
    if (has_next) {
      int nb = cur ^ 1;
      ushort4e xp;
#pragma unroll
      for (int j = 0; j < 4; ++j) xp[j] = f2bf(xv[j]);
      *(ushort4e*)&xs[nb][xrow][xcol] = xp;
#pragma unroll
      for (int i = 0; i < 6; ++i) {
        int p = tid + 256 * i;
        *(short8*)&wsh[nb][p >> 3][(p & 7) * 8] = wv[i];
      }
    }
    __syncthreads();
  }

  int lr = hi * 4;
#pragma unroll
  for (int tt = 0; tt < 3; ++tt) {
    int gt = w * 3 + tt;
    if (gt < 8) {
      unsigned short* dst = (gt < 4) ? Qb : Kb;
      int col = (gt & 3) * 16 + r;
#pragma unroll
      for (int v = 0; v < 4; ++v)
        dst[(size_t)(sbase + lr + v) * 64 + col] = f2bf(acc[tt][v]);
    } else {
      int d = (gt - 8) * 16 + r;
      ushort4e pk;
#pragma unroll
      for (int v = 0; v < 4; ++v) pk[v] = f2bf(acc[tt][v]);
      int bidx = sbase >> 12;
      int so = (sbase & 4095) + lr;
      *(ushort4e*)(Vt + ((size_t)(bidx * 64 + d)) * 4096 + so) = pk;
    }
  }
}

// ---------------- Kernel 3: flash attention (R7 body, + runtime nrep) --------
// nrep: idempotent internal repeats (runtime arg -> no unroll/CSE; each rep
// re-inits state, re-loads, re-writes identical outputs). Counter row dur/nrep
// = gapless per-rep attn cost, with full counters.
__global__ __launch_bounds__(256, 2) void attn_kernel(
    const unsigned short* __restrict__ Qb, const unsigned short* __restrict__ Kb,
    const unsigned short* __restrict__ Vt, float* __restrict__ Opart,
    float* __restrict__ Mpart, float* __restrict__ Lpart, int nrep) {
  int bid = blockIdx.x;
  int q = 127 - (bid >> 3);
  int b = (bid >> 2) & 1;
  int hh = bid & 3;
  int lane = threadIdx.x & 63;
  int p = threadIdx.x >> 6;
  int g = hh * 4 + p;
  int ql = lane & 31;
  int h = lane >> 5;
  int sbase = q * 32;

  __shared__ float sm[4][32];
  __shared__ float sl[4][32];
  __shared__ alignas(16) float Op[4][32][68];

  for (int rep = 0; rep < nrep; ++rep) {
    __syncthreads();   // LDS WAR guard across reps

    const unsigned short* Qp = Qb + ((size_t)(b * 4096 + sbase + ql)) * 64 + h * 8;
    short8 qf0 = *(const short8*)(Qp);
    short8 qf1 = *(const short8*)(Qp + 16);
    short8 qf2 = *(const short8*)(Qp + 32);
    short8 qf3 = *(const short8*)(Qp + 48);

    f32x16 o0, o1;
#pragma unroll
    for (int i = 0; i < 16; ++i) { o0[i] = 0.f; o1[i] = 0.f; }
    float m = NEGINF, l = 0.f;

    int npairs = (q + 2) >> 1;
    const unsigned short* Kbb = Kb + (size_t)b * 4096 * 64;
    const unsigned short* Vbb = Vt + ((size_t)(b * 64 + ql)) * 4096 + h * 8;

    short8 k0a, k0b, k0c, k0d, k1a, k1b, k1c, k1d;
    {
      const unsigned short* Kp = Kbb + (size_t)(g * 64 + ql) * 64 + h * 8;
      k0a = *(const short8*)(Kp);
      k0b = *(const short8*)(Kp + 16);
      k0c = *(const short8*)(Kp + 32);
      k0d = *(const short8*)(Kp + 48);
      k1a = *(const short8*)(Kp + 2048);
      k1b = *(const short8*)(Kp + 2048 + 16);
      k1c = *(const short8*)(Kp + 2048 + 32);
      k1d = *(const short8*)(Kp + 2048 + 48);
    }

    for (int j = g; j < npairs; j += 16) {
      int kbase = j * 64;
      const unsigned short* Vp = Vbb + kbase;
      short8 vf0 = *(const short8*)(Vp);
      short8 vf1 = *(const short8*)(Vp + 16);
      short8 vf2 = *(const short8*)(Vp + 32);
      short8 vf3 = *(const short8*)(Vp + 48);
      short8 vg0 = *(const short8*)(Vp + 32 * 4096);
      short8 vg1 = *(const short8*)(Vp + 32 * 4096 + 16);
      short8 vg2 = *(const short8*)(Vp + 32 * 4096 + 32);
      short8 vg3 = *(const short8*)(Vp + 32 * 4096 + 48);

      f32x16 st0, st1;
#pragma unroll
      for (int i = 0; i < 16; ++i) { st0[i] = 0.f; st1[i] = 0.f; }
      __builtin_amdgcn_s_setprio(1);
      st0 = mfma32(k0a, qf0, st0);
      st0 = mfma32(k0b, qf1, st0);
      st0 = mfma32(k0c, qf2, st0);
      st0 = mfma32(k0d, qf3, st0);
      st1 = mfma32(k1a, qf0, st1);
      st1 = mfma32(k1b, qf1, st1);
      st1 = mfma32(k1c, qf2, st1);
      st1 = mfma32(k1d, qf3, st1);
      __builtin_amdgcn_s_setprio(0);

      if (j + 16 < npairs) {
        const unsigned short* Kp = Kbb + (size_t)((j + 16) * 64 + ql) * 64 + h * 8;
        k0a = *(const short8*)(Kp);
        k0b = *(const short8*)(Kp + 16);
        k0c = *(const short8*)(Kp + 32);
        k0d = *(const short8*)(Kp + 48);
        k1a = *(const short8*)(Kp + 2048);
        k1b = *(const short8*)(Kp + 2048 + 16);
        k1c = *(const short8*)(Kp + 2048 + 32);
        k1d = *(const short8*)(Kp + 2048 + 48);
      }

      if (2 * j == q) {
#pragma unroll
        for (int rg = 0; rg < 16; ++rg) {
          int kvl = (rg & 3) + 8 * (rg >> 2) + 4 * h;
          if (kvl > ql) st0[rg] = NEGINF;
          st1[rg] = NEGINF;
        }
      } else if (2 * j + 1 == q) {
#pragma unroll
        for (int rg = 0; rg < 16; ++rg) {
          int kvl = (rg & 3) + 8 * (rg >> 2) + 4 * h;
          if (kvl > ql) st1[rg] = NEGINF;
        }
      }

      float mx[16];
#pragma unroll
      for (int i = 0; i < 16; ++i) mx[i] = fmaxf(st0[i], st1[i]);
#pragma unroll
      for (int s = 8; s >= 1; s >>= 1)
#pragma unroll
        for (int i = 0; i < s; ++i) mx[i] = fmaxf(mx[i], mx[i + s]);
      float tm = fmaxf(mx[0], __shfl_xor(mx[0], 32));
      float nm = fmaxf(m, tm);
      float alpha = exp2f(m - nm);
#pragma unroll
      for (int i = 0; i < 16; ++i) {
        st0[i] = exp2f(st0[i] - nm);
        st1[i] = exp2f(st1[i] - nm);
      }
      float sv[16];
#pragma unroll
      for (int i = 0; i < 16; ++i) sv[i] = st0[i] + st1[i];
#pragma unroll
      for (int s = 8; s >= 1; s >>= 1)
#pragma unroll
        for (int i = 0; i < s; ++i) sv[i] += sv[i + s];
      float sum = sv[0] + __shfl_xor(sv[0], 32);
      l = l * alpha + sum;
      m = nm;
#pragma unroll
      for (int i = 0; i < 16; ++i) { o0[i] *= alpha; o1[i] *= alpha; }

      unsigned int pw0[8], pw1[8], sw0[8], sw1[8];
#pragma unroll
      for (int t = 0; t < 8; ++t) {
        pw0[t] = (unsigned int)f2bf(st0[2 * t]) | ((unsigned int)f2bf(st0[2 * t + 1]) << 16);
        pw1[t] = (unsigned int)f2bf(st1[2 * t]) | ((unsigned int)f2bf(st1[2 * t + 1]) << 16);
      }
#pragma unroll
      for (int t = 0; t < 8; ++t) {
        sw0[t] = __shfl_xor(pw0[t], 32);
        sw1[t] = __shfl_xor(pw1[t], 32);
      }
      uint4e bw0 = {h ? sw0[2] : pw0[0], h ? sw0[3] : pw0[1], h ? pw0[2] : sw0[0], h ? pw0[3] : sw0[1]};
      uint4e bw1 = {h ? sw0[6] : pw0[4], h ? sw0[7] : pw0[5], h ? pw0[6] : sw0[4], h ? pw0[7] : sw0[5]};
      uint4e bw2 = {h ? sw1[2] : pw1[0], h ? sw1[3] : pw1[1], h ? pw1[2] : sw1[0], h ? pw1[3] : sw1[1]};
      uint4e bw3 = {h ? sw1[6] : pw1[4], h ? sw1[7] : pw1[5], h ? pw1[6] : sw1[4], h ? pw1[7] : sw1[5]};
      short8 pb0 = __builtin_bit_cast(short8, bw0);
      short8 pb1 = __builtin_bit_cast(short8, bw1);
      short8 pb2 = __builtin_bit_cast(short8, bw2);
      short8 pb3 = __builtin_bit_cast(short8, bw3);

      __builtin_amdgcn_s_setprio(1);
      o0 = mfma32(vf0, pb0, o0);
      o0 = mfma32(vf1, pb1, o0);
      o0 = mfma32(vf2, pb2, o0);
      o0 = mfma32(vf3, pb3, o0);
      o1 = mfma32(vg0, pb0, o1);
      o1 = mfma32(vg1, pb1, o1);
      o1 = mfma32(vg2, pb2, o1);
      o1 = mfma32(vg3, pb3, o1);
      __builtin_amdgcn_s_setprio(0);
    }

    if (h == 0) sm[p][ql] = m;
    __syncthreads();
    float gm = sm[0][ql];
#pragma unroll
    for (int i = 1; i < 4; ++i) gm = fmaxf(gm, sm[i][ql]);
    float alpha = exp2f(m - gm);
    if (h == 0) sl[p][ql] = alpha * l;
    float* Ob = &Op[p][ql][0];
#pragma unroll
    for (int u = 0; u < 4; ++u) {
      f32x4 w0 = {alpha * o0[4 * u], alpha * o0[4 * u + 1], alpha * o0[4 * u + 2], alpha * o0[4 * u + 3]};
      *(f32x4*)(Ob + u * 8 + h * 4) = w0;
      f32x4 w1 = {alpha * o1[4 * u], alpha * o1[4 * u + 1], alpha * o1[4 * u + 2], alpha * o1[4 * u + 3]};
      *(f32x4*)(Ob + 32 + u * 8 + h * 4) = w1;
    }
    __syncthreads();

    float* Od = Opart + (size_t)bid * 2048;
#pragma unroll
    for (int i = 0; i < 2; ++i) {
      int task = threadIdx.x + i * 256;
      int row = task >> 4;
      int c4 = (task & 15) * 4;
      f32x4 accv = *(const f32x4*)(&Op[0][row][c4]);
#pragma unroll
      for (int pp = 1; pp < 4; ++pp) accv += *(const f32x4*)(&Op[pp][row][c4]);
      *(f32x4*)(Od + row * 64 + c4) = accv;
    }
    if (threadIdx.x < 32) {
      int row = threadIdx.x;
      float gmv = fmaxf(fmaxf(sm[0][row], sm[1][row]), fmaxf(sm[2][row], sm[3][row]));
      Mpart[(size_t)bid * 32 + row] = gmv;
      Lpart[(size_t)bid * 32 + row] = sl[0][row] + sl[1][row] + sl[2][row] + sl[3][row];
    }
  }
}

// ---------------- Kernel 4: combine 4 partials per q-tile --------------------
__global__ __launch_bounds__(256) void combine_kernel(
    const float* __restrict__ Opart, const float* __restrict__ Mpart,
    const float* __restrict__ Lpart, float* __restrict__ out) {
  int gid = blockIdx.x * 256 + threadIdx.x;
  int c4 = (gid & 15) * 4;
  int row = gid >> 4;
  int r = row & 31;
  int qg = row >> 5;
  int b = qg >> 7, q = qg & 127;
  int base = (127 - q) * 8 + b * 4;

  float mm[4];
  float gm = NEGINF;
#pragma unroll
  for (int i = 0; i < 4; ++i) {
    mm[i] = Mpart[(size_t)(base + i) * 32 + r];
    gm = fmaxf(gm, mm[i]);
  }
  float L = 0.f;
  f32x4 o = {0.f, 0.f, 0.f, 0.f};
#pragma unroll
  for (int i = 0; i < 4; ++i) {
    float e = exp2f(mm[i] - gm);
    L += e * Lpart[(size_t)(base + i) * 32 + r];
    f32x4 ov = *(const f32x4*)(Opart + (size_t)(base + i) * 2048 + r * 64 + c4);
    o += e * ov;
  }
  float invl = 1.0f / L;
  f32x4 res = {o[0] * invl, o[1] * invl, o[2] * invl, o[3] * invl};
  *(f32x4*)(out + (size_t)row * 64 + c4) = res;
}

// ---------------- launcher ---------------------------------------------------
extern "C" void kernel_launch(void* const* d_in, const int* in_sizes, int n_in,
                              void* d_out, int out_size, void* d_ws, size_t ws_size,
                              hipStream_t stream) {
  const float* x  = (const float*)d_in[0];
  const float* Wq = (const float*)d_in[1];
  const float* Wk = (const float*)d_in[2];
  const float* Wv = (const float*)d_in[3];
  float* out = (float*)d_out;

  if (ws_size < 12189696) return;  // tripwire

  char* ws = (char*)d_ws;
  unsigned short* Wt = (unsigned short*)(ws + 0);          //   393216 B
  unsigned short* Qb = (unsigned short*)(ws + 393216);     //  1048576 B
  unsigned short* Kb = (unsigned short*)(ws + 1441792);    //  1048576 B
  unsigned short* Vt = (unsigned short*)(ws + 2490368);    //  1048576 B
  float* Opart = (float*)(ws + 3538944);                   //  8388608 B
  float* Mpart = (float*)(ws + 11927552);                  //   131072 B
  float* Lpart = (float*)(ws + 12058624);                  //   131072 B

  wprep_kernel<<<24, 256, 0, stream>>>(Wq, Wk, Wv, Wt);
  // qkv2 masked x1 (timing only; old qkv below overwrites its output)
  qkv_proj2_kernel<<<512, 256, 0, stream>>>(x, Wt, Qb, Kb, Vt);
  qkv_proj_kernel<<<256, 512, 0, stream>>>(x, Wt, Qb, Kb, Vt);
  // attn with 4 idempotent INTERNAL reps -> ~4x-dur counter row in top-5
  attn_kernel<<<1024, 256, 0, stream>>>(Qb, Kb, Vt, Opart, Mpart, Lpart, 4);
  combine_kernel<<<512, 256, 0, stream>>>(Opart, Mpart, Lpart, out);
}

// Round 13
// 158.096 us; speedup vs baseline: 2.2988x; 1.2196x over previous
//
#include <hip/hip_runtime.h>
#include <hip/hip_bf16.h>

// Fused causal self-attention, B=2, S=4096, E=1024, D=64 (single head).
// R13: qkv2 (deep-prefetch LDS GEMM, measured ~0-3us masked) PROMOTED to
//      production (old qkv ~21.6us deleted). attn: 32-way KV split
//      (2048 blocks x 4 waves, worst wave 2 iters, launch_bounds(256,4)).
//      Combine: 8 partials/q-tile. Budget: OH~77 fixed; target kernels ~30us.

typedef short short8 __attribute__((ext_vector_type(8)));
typedef float f32x4 __attribute__((ext_vector_type(4)));
typedef float f32x16 __attribute__((ext_vector_type(16)));
typedef unsigned int uint4e __attribute__((ext_vector_type(4)));
typedef unsigned short ushort4e __attribute__((ext_vector_type(4)));

#define NEGINF (-3.0e38f)
#define SCQ 0.18033688011112042f   // 0.125 * log2(e): S in log2 domain -> exp2

static __device__ __forceinline__ unsigned short f2bf(float f) {
  __hip_bfloat16 h = __float2bfloat16(f);
  return __builtin_bit_cast(unsigned short, h);
}
static __device__ __forceinline__ f32x16 mfma32(short8 a, short8 b, f32x16 c) {
  return __builtin_amdgcn_mfma_f32_32x32x16_bf16(a, b, c, 0, 0, 0);
}

// ---------------- Kernel 1: W prep (coalesced transpose via LDS) -------------
__global__ __launch_bounds__(256) void wprep_kernel(
    const float* __restrict__ Wq, const float* __restrict__ Wk,
    const float* __restrict__ Wv, unsigned short* __restrict__ Wt) {
  int w = blockIdx.x >> 3;
  int kc = blockIdx.x & 7;
  int k0 = kc * 128;
  const float* W = (w == 0) ? Wq : ((w == 1) ? Wk : Wv);
  float sc = (w == 0) ? SCQ : 1.0f;

  __shared__ unsigned short lt[128][66];
#pragma unroll
  for (int i = 0; i < 32; ++i) {
    int e = i * 256 + threadIdx.x;
    int k = e >> 6, n = e & 63;
    lt[k][n] = f2bf(W[(size_t)(k0 + k) * 64 + n] * sc);
  }
  __syncthreads();
#pragma unroll
  for (int i = 0; i < 32; ++i) {
    int e = i * 256 + threadIdx.x;
    int n = e >> 7, k = e & 127;
    Wt[(size_t)(w * 64 + n) * 1024 + k0 + k] = lt[k][n];
  }
}

// ---------------- Kernel 2: QKV projection (deep-prefetch, production) -------
// 512 blocks x 256 threads (4 waves, 2 blocks/CU). Block = 16 rows x 192 cols;
// K-chunks of 64 (16 chunks), double-buffered LDS, padded 72-short rows.
// Per chunk per thread: 1 f32x4 x-load + 6 short8 Wt-loads = 112B in flight.
__global__ __launch_bounds__(256, 2) void qkv_proj_kernel(
    const float* __restrict__ x, const unsigned short* __restrict__ Wt,
    unsigned short* __restrict__ Qb, unsigned short* __restrict__ Kb,
    unsigned short* __restrict__ Vt) {
  int tid = threadIdx.x;
  int lane = tid & 63;
  int w = tid >> 6;           // wave 0..3 = col group of 48
  int r = lane & 15;
  int hi = lane >> 4;
  int sbase = blockIdx.x * 16;

  __shared__ alignas(16) unsigned short xs[2][16][72];     //  4.5 KB
  __shared__ alignas(16) unsigned short wsh[2][192][72];   // 54.0 KB

  int xrow = tid >> 4;              // 0..15
  int xcol = (tid & 15) * 4;        // 0..60
  const float* xg = x + (size_t)(sbase + xrow) * 1024 + xcol;

  f32x4 acc[3];
#pragma unroll
  for (int t = 0; t < 3; ++t)
#pragma unroll
    for (int i = 0; i < 4; ++i) acc[t][i] = 0.f;

  {
    f32x4 xv = *(const f32x4*)(xg);
    ushort4e xp;
#pragma unroll
    for (int j = 0; j < 4; ++j) xp[j] = f2bf(xv[j]);
    *(ushort4e*)&xs[0][xrow][xcol] = xp;
#pragma unroll
    for (int i = 0; i < 6; ++i) {
      int p = tid + 256 * i;        // 0..1535: row = p>>3, off = (p&7)*8
      short8 wv = *(const short8*)(Wt + (size_t)(p >> 3) * 1024 + (p & 7) * 8);
      *(short8*)&wsh[0][p >> 3][(p & 7) * 8] = wv;
    }
  }
  __syncthreads();

  for (int c = 0; c < 16; ++c) {
    int cur = c & 1;
    bool has_next = (c + 1) < 16;
    f32x4 xv;
    short8 wv[6];
    if (has_next) {                 // issue next-chunk loads (deep in-flight)
      int k0 = (c + 1) * 64;
      xv = *(const f32x4*)(xg + k0);
#pragma unroll
      for (int i = 0; i < 6; ++i) {
        int p = tid + 256 * i;
        wv[i] = *(const short8*)(Wt + (size_t)(p >> 3) * 1024 + k0 + (p & 7) * 8);
      }
    }
    short8 af0 = *(const short8*)&xs[cur][r][hi * 8];
    short8 af1 = *(const short8*)&xs[cur][r][32 + hi * 8];
#pragma unroll
    for (int tt = 0; tt < 3; ++tt) {
      const unsigned short* bp = &wsh[cur][w * 48 + tt * 16 + r][hi * 8];
      short8 bf0 = *(const short8*)bp;
      short8 bf1 = *(const short8*)(bp + 32);
      acc[tt] = __builtin_amdgcn_mfma_f32_16x16x32_bf16(af0, bf0, acc[tt], 0, 0, 0);
      acc[tt] = __builtin_amdgcn_mfma_f32_16x16x32_bf16(af1, bf1, acc[tt], 0, 0, 0);
    }
    if (has_next) {
      int nb = cur ^ 1;
      ushort4e xp;
#pragma unroll
      for (int j = 0; j < 4; ++j) xp[j] = f2bf(xv[j]);
      *(ushort4e*)&xs[nb][xrow][xcol] = xp;
#pragma unroll
      for (int i = 0; i < 6; ++i) {
        int p = tid + 256 * i;
        *(short8*)&wsh[nb][p >> 3][(p & 7) * 8] = wv[i];
      }
    }
    __syncthreads();
  }

  int lr = hi * 4;
#pragma unroll
  for (int tt = 0; tt < 3; ++tt) {
    int gt = w * 3 + tt;
    if (gt < 8) {
      unsigned short* dst = (gt < 4) ? Qb : Kb;
      int col = (gt & 3) * 16 + r;
#pragma unroll
      for (int v = 0; v < 4; ++v)
        dst[(size_t)(sbase + lr + v) * 64 + col] = f2bf(acc[tt][v]);
    } else {
      int d = (gt - 8) * 16 + r;
      ushort4e pk;
#pragma unroll
      for (int v = 0; v < 4; ++v) pk[v] = f2bf(acc[tt][v]);
      int bidx = sbase >> 12;
      int so = (sbase & 4095) + lr;
      *(ushort4e*)(Vt + ((size_t)(bidx * 64 + d)) * 4096 + so) = pk;
    }
  }
}

// ---------------- Kernel 3: flash attention (32-way KV split) ----------------
// 2048 blocks x 256 threads (4 waves). bid -> q = 127-(bid>>4) (heavy first),
// b = (bid>>3)&1, hh = bid&7. Wave part g = hh*4 + p handles KV pairs
// g, g+32 (pair = 64 rows). Worst wave: 2 iterations.
// S^T = K.Q^T : C/D col = lane&31 = q-row ; kv = (reg&3)+8*(reg>>2)+4*(lane>>5)
__global__ __launch_bounds__(256, 4) void attn_kernel(
    const unsigned short* __restrict__ Qb, const unsigned short* __restrict__ Kb,
    const unsigned short* __restrict__ Vt, float* __restrict__ Opart,
    float* __restrict__ Mpart, float* __restrict__ Lpart) {
  int bid = blockIdx.x;             // 0..2047
  int q = 127 - (bid >> 4);         // heavy q first
  int b = (bid >> 3) & 1;
  int hh = bid & 7;
  int lane = threadIdx.x & 63;
  int p = threadIdx.x >> 6;         // 0..3
  int g = hh * 4 + p;               // KV part 0..31
  int ql = lane & 31;
  int h = lane >> 5;
  int sbase = q * 32;

  __shared__ float sm[4][32];
  __shared__ float sl[4][32];
  __shared__ alignas(16) float Op[4][32][68];

  const unsigned short* Qp = Qb + ((size_t)(b * 4096 + sbase + ql)) * 64 + h * 8;
  short8 qf0 = *(const short8*)(Qp);
  short8 qf1 = *(const short8*)(Qp + 16);
  short8 qf2 = *(const short8*)(Qp + 32);
  short8 qf3 = *(const short8*)(Qp + 48);

  f32x16 o0, o1;
#pragma unroll
  for (int i = 0; i < 16; ++i) { o0[i] = 0.f; o1[i] = 0.f; }
  float m = NEGINF, l = 0.f;

  int npairs = (q + 2) >> 1;
  const unsigned short* Kbb = Kb + (size_t)b * 4096 * 64;
  const unsigned short* Vbb = Vt + ((size_t)(b * 64 + ql)) * 4096 + h * 8;

  short8 k0a, k0b, k0c, k0d, k1a, k1b, k1c, k1d;
  if (g < npairs) {
    const unsigned short* Kp = Kbb + (size_t)(g * 64 + ql) * 64 + h * 8;
    k0a = *(const short8*)(Kp);
    k0b = *(const short8*)(Kp + 16);
    k0c = *(const short8*)(Kp + 32);
    k0d = *(const short8*)(Kp + 48);
    k1a = *(const short8*)(Kp + 2048);
    k1b = *(const short8*)(Kp + 2048 + 16);
    k1c = *(const short8*)(Kp + 2048 + 32);
    k1d = *(const short8*)(Kp + 2048 + 48);
  }

  for (int j = g; j < npairs; j += 32) {
    int kbase = j * 64;
    const unsigned short* Vp = Vbb + kbase;
    short8 vf0 = *(const short8*)(Vp);
    short8 vf1 = *(const short8*)(Vp + 16);
    short8 vf2 = *(const short8*)(Vp + 32);
    short8 vf3 = *(const short8*)(Vp + 48);
    short8 vg0 = *(const short8*)(Vp + 32 * 4096);
    short8 vg1 = *(const short8*)(Vp + 32 * 4096 + 16);
    short8 vg2 = *(const short8*)(Vp + 32 * 4096 + 32);
    short8 vg3 = *(const short8*)(Vp + 32 * 4096 + 48);

    f32x16 st0, st1;
#pragma unroll
    for (int i = 0; i < 16; ++i) { st0[i] = 0.f; st1[i] = 0.f; }
    __builtin_amdgcn_s_setprio(1);
    st0 = mfma32(k0a, qf0, st0);
    st0 = mfma32(k0b, qf1, st0);
    st0 = mfma32(k0c, qf2, st0);
    st0 = mfma32(k0d, qf3, st0);
    st1 = mfma32(k1a, qf0, st1);
    st1 = mfma32(k1b, qf1, st1);
    st1 = mfma32(k1c, qf2, st1);
    st1 = mfma32(k1d, qf3, st1);
    __builtin_amdgcn_s_setprio(0);

    if (j + 32 < npairs) {          // prefetch next pair's K
      const unsigned short* Kp = Kbb + (size_t)((j + 32) * 64 + ql) * 64 + h * 8;
      k0a = *(const short8*)(Kp);
      k0b = *(const short8*)(Kp + 16);
      k0c = *(const short8*)(Kp + 32);
      k0d = *(const short8*)(Kp + 48);
      k1a = *(const short8*)(Kp + 2048);
      k1b = *(const short8*)(Kp + 2048 + 16);
      k1c = *(const short8*)(Kp + 2048 + 32);
      k1d = *(const short8*)(Kp + 2048 + 48);
    }

    if (2 * j == q) {
#pragma unroll
      for (int rg = 0; rg < 16; ++rg) {
        int kvl = (rg & 3) + 8 * (rg >> 2) + 4 * h;
        if (kvl > ql) st0[rg] = NEGINF;
        st1[rg] = NEGINF;
      }
    } else if (2 * j + 1 == q) {
#pragma unroll
      for (int rg = 0; rg < 16; ++rg) {
        int kvl = (rg & 3) + 8 * (rg >> 2) + 4 * h;
        if (kvl > ql) st1[rg] = NEGINF;
      }
    }

    // ---- online softmax over 32 values (log2 domain) ----
    float mx[16];
#pragma unroll
    for (int i = 0; i < 16; ++i) mx[i] = fmaxf(st0[i], st1[i]);
#pragma unroll
    for (int s = 8; s >= 1; s >>= 1)
#pragma unroll
      for (int i = 0; i < s; ++i) mx[i] = fmaxf(mx[i], mx[i + s]);
    float tm = fmaxf(mx[0], __shfl_xor(mx[0], 32));
    float nm = fmaxf(m, tm);
    float alpha = exp2f(m - nm);
#pragma unroll
    for (int i = 0; i < 16; ++i) {
      st0[i] = exp2f(st0[i] - nm);
      st1[i] = exp2f(st1[i] - nm);
    }
    float sv[16];
#pragma unroll
    for (int i = 0; i < 16; ++i) sv[i] = st0[i] + st1[i];
#pragma unroll
    for (int s = 8; s >= 1; s >>= 1)
#pragma unroll
      for (int i = 0; i < s; ++i) sv[i] += sv[i + s];
    float sum = sv[0] + __shfl_xor(sv[0], 32);
    l = l * alpha + sum;
    m = nm;
#pragma unroll
    for (int i = 0; i < 16; ++i) { o0[i] *= alpha; o1[i] *= alpha; }

    // ---- pack P -> bf16 B-frags (shfl_xor exchange) ----
    unsigned int pw0[8], pw1[8], sw0[8], sw1[8];
#pragma unroll
    for (int t = 0; t < 8; ++t) {
      pw0[t] = (unsigned int)f2bf(st0[2 * t]) | ((unsigned int)f2bf(st0[2 * t + 1]) << 16);
      pw1[t] = (unsigned int)f2bf(st1[2 * t]) | ((unsigned int)f2bf(st1[2 * t + 1]) << 16);
    }
#pragma unroll
    for (int t = 0; t < 8; ++t) {
      sw0[t] = __shfl_xor(pw0[t], 32);
      sw1[t] = __shfl_xor(pw1[t], 32);
    }
    uint4e bw0 = {h ? sw0[2] : pw0[0], h ? sw0[3] : pw0[1], h ? pw0[2] : sw0[0], h ? pw0[3] : sw0[1]};
    uint4e bw1 = {h ? sw0[6] : pw0[4], h ? sw0[7] : pw0[5], h ? pw0[6] : sw0[4], h ? pw0[7] : sw0[5]};
    uint4e bw2 = {h ? sw1[2] : pw1[0], h ? sw1[3] : pw1[1], h ? pw1[2] : sw1[0], h ? pw1[3] : sw1[1]};
    uint4e bw3 = {h ? sw1[6] : pw1[4], h ? sw1[7] : pw1[5], h ? pw1[6] : sw1[4], h ? pw1[7] : sw1[5]};
    short8 pb0 = __builtin_bit_cast(short8, bw0);
    short8 pb1 = __builtin_bit_cast(short8, bw1);
    short8 pb2 = __builtin_bit_cast(short8, bw2);
    short8 pb3 = __builtin_bit_cast(short8, bw3);

    __builtin_amdgcn_s_setprio(1);
    o0 = mfma32(vf0, pb0, o0);
    o0 = mfma32(vf1, pb1, o0);
    o0 = mfma32(vf2, pb2, o0);
    o0 = mfma32(vf3, pb3, o0);
    o1 = mfma32(vg0, pb0, o1);
    o1 = mfma32(vg1, pb1, o1);
    o1 = mfma32(vg2, pb2, o1);
    o1 = mfma32(vg3, pb3, o1);
    __builtin_amdgcn_s_setprio(0);
  }

  // ---- LDS combine of this block's 4 waves -> global partial ----
  if (h == 0) sm[p][ql] = m;
  __syncthreads();
  float gm = sm[0][ql];
#pragma unroll
  for (int i = 1; i < 4; ++i) gm = fmaxf(gm, sm[i][ql]);
  float alpha = exp2f(m - gm);      // 0 for empty waves; gm=NEGINF case -> l=0
  if (h == 0) sl[p][ql] = alpha * l;
  float* Ob = &Op[p][ql][0];
#pragma unroll
  for (int u = 0; u < 4; ++u) {
    f32x4 w0 = {alpha * o0[4 * u], alpha * o0[4 * u + 1], alpha * o0[4 * u + 2], alpha * o0[4 * u + 3]};
    *(f32x4*)(Ob + u * 8 + h * 4) = w0;
    f32x4 w1 = {alpha * o1[4 * u], alpha * o1[4 * u + 1], alpha * o1[4 * u + 2], alpha * o1[4 * u + 3]};
    *(f32x4*)(Ob + 32 + u * 8 + h * 4) = w1;
  }
  __syncthreads();

  float* Od = Opart + (size_t)bid * 2048;
#pragma unroll
  for (int i = 0; i < 2; ++i) {
    int task = threadIdx.x + i * 256;
    int row = task >> 4;
    int c4 = (task & 15) * 4;
    f32x4 accv = *(const f32x4*)(&Op[0][row][c4]);
#pragma unroll
    for (int pp = 1; pp < 4; ++pp) accv += *(const f32x4*)(&Op[pp][row][c4]);
    *(f32x4*)(Od + row * 64 + c4) = accv;
  }
  if (threadIdx.x < 32) {
    int row = threadIdx.x;
    float gmv = fmaxf(fmaxf(sm[0][row], sm[1][row]), fmaxf(sm[2][row], sm[3][row]));
    Mpart[(size_t)bid * 32 + row] = gmv;
    Lpart[(size_t)bid * 32 + row] = sl[0][row] + sl[1][row] + sl[2][row] + sl[3][row];
  }
}

// ---------------- Kernel 4: combine 8 partials per q-tile --------------------
__global__ __launch_bounds__(256) void combine_kernel(
    const float* __restrict__ Opart, const float* __restrict__ Mpart,
    const float* __restrict__ Lpart, float* __restrict__ out) {
  int gid = blockIdx.x * 256 + threadIdx.x;   // 0..131071
  int c4 = (gid & 15) * 4;
  int row = gid >> 4;                         // b*4096 + s
  int r = row & 31;
  int qg = row >> 5;                          // b*128 + q
  int b = qg >> 7, q = qg & 127;
  int base = (127 - q) * 16 + b * 8;          // 8 partial blocks

  float mm[8];
  float gm = NEGINF;
#pragma unroll
  for (int i = 0; i < 8; ++i) {
    mm[i] = Mpart[(size_t)(base + i) * 32 + r];
    gm = fmaxf(gm, mm[i]);
  }
  float L = 0.f;
  f32x4 o = {0.f, 0.f, 0.f, 0.f};
#pragma unroll
  for (int i = 0; i < 8; ++i) {
    float e = exp2f(mm[i] - gm);
    L += e * Lpart[(size_t)(base + i) * 32 + r];
    f32x4 ov = *(const f32x4*)(Opart + (size_t)(base + i) * 2048 + r * 64 + c4);
    o += e * ov;
  }
  float invl = 1.0f / L;
  f32x4 res = {o[0] * invl, o[1] * invl, o[2] * invl, o[3] * invl};
  *(f32x4*)(out + (size_t)row * 64 + c4) = res;
}

// ---------------- launcher ---------------------------------------------------
extern "C" void kernel_launch(void* const* d_in, const int* in_sizes, int n_in,
                              void* d_out, int out_size, void* d_ws, size_t ws_size,
                              hipStream_t stream) {
  const float* x  = (const float*)d_in[0];
  const float* Wq = (const float*)d_in[1];
  const float* Wk = (const float*)d_in[2];
  const float* Wv = (const float*)d_in[3];
  float* out = (float*)d_out;

  if (ws_size < 20840448) return;  // tripwire (ws ~268 MB measured)

  char* ws = (char*)d_ws;
  unsigned short* Wt = (unsigned short*)(ws + 0);          //   393216 B
  unsigned short* Qb = (unsigned short*)(ws + 393216);     //  1048576 B
  unsigned short* Kb = (unsigned short*)(ws + 1441792);    //  1048576 B
  unsigned short* Vt = (unsigned short*)(ws + 2490368);    //  1048576 B
  float* Opart = (float*)(ws + 3538944);                   // 16777216 B
  float* Mpart = (float*)(ws + 20316160);                  //   262144 B
  float* Lpart = (float*)(ws + 20578304);                  //   262144 B

  wprep_kernel<<<24, 256, 0, stream>>>(Wq, Wk, Wv, Wt);
  qkv_proj_kernel<<<512, 256, 0, stream>>>(x, Wt, Qb, Kb, Vt);
  attn_kernel<<<2048, 256, 0, stream>>>(Qb, Kb, Vt, Opart, Mpart, Lpart);
  combine_kernel<<<512, 256, 0, stream>>>(Opart, Mpart, Lpart, out);
}